// Round 3
// baseline (462.204 us; speedup 1.0000x reference)
//
#include <hip/hip_runtime.h>
#include <stdint.h>

// FPQuantizer: elementwise fp8_e4m3-style "flex" quantization (bit-exact vs numpy).
//   bias = bf16(16 - log2(448) + log2(1.9375) - 1) = 7.15625 (exact in fp32)
//   e = max(floor(log2|x| + bias), 1)         [row-max clip is an identity -> elementwise]
//   scale = 2^(e - 5 - bias) = 2^(e-13) * 2^(27/32)
//   out = rint(x/scale) * scale
//
// Exact floor via exponent/mantissa bits: floor(log2|x| + 7.15625) = E + 7 + (mant > T),
//   T = fp32(2^(27/32)) = 15055111/2^23 = 1.79470908641815f (correctly-rounded, and the
//   boundary case mant==T provably gives identical output either way).
// scale bit-assembled: ((e+114)<<23) | 0x65B907  == correctly-rounded exp2f(e-12.15625).
// Division must stay IEEE: at e=9 the quant step (0.1122) exceeds the absmax threshold
// (0.1075), so a single reciprocal-induced rounding flip on a large element would fail.

typedef float f32x4 __attribute__((ext_vector_type(4)));

__device__ __forceinline__ float fpq_one(float xv) {
    unsigned b = __float_as_uint(xv) & 0x7FFFFFFFu;
    int expfield = (int)(b >> 23);
    float mant = __uint_as_float((b & 0x7FFFFFu) | 0x3F800000u);
    int e = expfield - 127 + 7 + (mant > 1.79470908641815f ? 1 : 0);
    if (expfield == 0) e = 1;      // zero / denormal -> clamped path (output 0 anyway)
    if (e < 1) e = 1;              // log_scales = max(log_scales, 1)
    float scale = __int_as_float(((e + 114) << 23) | 0x65B907);
    float q = xv / scale;          // IEEE fp32 div, matches np
    float r = __builtin_rintf(q);  // round half-to-even, matches np.round
    return r * scale;
}

// 8 elements (two float4s) per thread; plain vector loads (m13's 6.29 TB/s copy
// pattern), nontemporal stores (output is never re-read).
__global__ __launch_bounds__(256) void fpq_vec8(const float* __restrict__ in,
                                                float* __restrict__ out, int n8) {
    int idx = blockIdx.x * blockDim.x + threadIdx.x;
    if (idx >= n8) return;
    const f32x4* in4 = (const f32x4*)in;
    f32x4* out4 = (f32x4*)out;
    f32x4 v0 = in4[2 * idx + 0];
    f32x4 v1 = in4[2 * idx + 1];
    f32x4 r0, r1;
    r0.x = fpq_one(v0.x); r0.y = fpq_one(v0.y);
    r0.z = fpq_one(v0.z); r0.w = fpq_one(v0.w);
    r1.x = fpq_one(v1.x); r1.y = fpq_one(v1.y);
    r1.z = fpq_one(v1.z); r1.w = fpq_one(v1.w);
    __builtin_nontemporal_store(r0, &out4[2 * idx + 0]);
    __builtin_nontemporal_store(r1, &out4[2 * idx + 1]);
}

__global__ __launch_bounds__(256) void fpq_tail(const float* __restrict__ in,
                                                float* __restrict__ out,
                                                int start, int n) {
    int idx = start + blockIdx.x * blockDim.x + threadIdx.x;
    if (idx >= n) return;
    out[idx] = fpq_one(in[idx]);
}

extern "C" void kernel_launch(void* const* d_in, const int* in_sizes, int n_in,
                              void* d_out, int out_size, void* d_ws, size_t ws_size,
                              hipStream_t stream) {
    const float* x = (const float*)d_in[0];
    float* out = (float*)d_out;
    int n = in_sizes[0];           // 8192*8192 = 67108864
    int n8 = n / 8;
    if (n8 > 0) {
        int block = 256;
        int grid = (n8 + block - 1) / block;   // 32768 blocks
        fpq_vec8<<<grid, block, 0, stream>>>(x, out, n8);
    }
    int tail_start = n8 * 8;
    int tail = n - tail_start;
    if (tail > 0) {
        fpq_tail<<<1, 64, 0, stream>>>(x, out, tail_start, n);
    }
}

// Round 4
// 418.762 us; speedup vs baseline: 1.1037x; 1.1037x over previous
//
#include <hip/hip_runtime.h>
#include <stdint.h>

// FPQuantizer: elementwise fp8_e4m3-style "flex" quantization (bit-exact vs numpy).
//   bias = bf16(16 - log2(448) + log2(1.9375) - 1) = 7.15625 (exact in fp32)
//   e = max(floor(log2|x| + bias), 1)         [row-max clip is an identity -> elementwise]
//   scale = 2^(e - 5 - bias) = 2^(e-13) * 2^(27/32)
//   out = rint(x/scale) * scale
//
// Exact floor via exponent/mantissa bits: floor(log2|x| + 7.15625) = E + 7 + (mant > T),
//   T = fp32(2^(27/32)) = 15055111/2^23 = 1.79470908641815f (correctly-rounded; the
//   boundary case mant==T provably gives identical output either way).
// scale bit-assembled: ((e+114)<<23) | 0x65B907  == correctly-rounded exp2f(e-12.15625).
// Division stays IEEE: at e=9 the quant step (0.1122) exceeds the absmax threshold
// (0.1075), so a reciprocal-multiply rounding flip on a large element would fail.
//
// Memory structure (R3 post-mortem):
//  - ONE float4 per thread, lane-contiguous: each wave ld/st instruction covers a
//    contiguous 1 KB span (R3's 2-float4/thread stride-32B pattern doubled cache-line
//    requests per instruction -> 2.6 TB/s; R2's contiguous vec4 was ~40% faster).
//  - PLAIN loads: harness restore leaves the 256 MiB input L3-resident; R3 measured
//    FETCH_SIZE = 134 MB = half the input served from Infinity Cache. NT loads (R2)
//    bypass L3 and refetch everything from HBM.
//  - NT stores: output is never re-read; lane-contiguous full-line writes avoid the
//    partial-sector RMW inflation seen in R3 (WRITE 314 MB vs 268 MB ideal).

typedef float f32x4 __attribute__((ext_vector_type(4)));

__device__ __forceinline__ float fpq_one(float xv) {
    unsigned b = __float_as_uint(xv) & 0x7FFFFFFFu;
    int expfield = (int)(b >> 23);
    float mant = __uint_as_float((b & 0x7FFFFFu) | 0x3F800000u);
    int e = expfield - 127 + 7 + (mant > 1.79470908641815f ? 1 : 0);
    if (expfield == 0) e = 1;      // zero / denormal -> clamped path (output 0 anyway)
    if (e < 1) e = 1;              // log_scales = max(log_scales, 1)
    float scale = __int_as_float(((e + 114) << 23) | 0x65B907);
    float q = xv / scale;          // IEEE fp32 div, matches np
    float r = __builtin_rintf(q);  // round half-to-even, matches np.round
    return r * scale;
}

__global__ __launch_bounds__(256) void fpq_vec4(const float* __restrict__ in,
                                                float* __restrict__ out, int n4) {
    int idx = blockIdx.x * blockDim.x + threadIdx.x;
    if (idx >= n4) return;
    const f32x4* in4 = (const f32x4*)in;
    f32x4* out4 = (f32x4*)out;
    f32x4 v = in4[idx];            // plain load: hits L3-resident input
    f32x4 res;
    res.x = fpq_one(v.x);
    res.y = fpq_one(v.y);
    res.z = fpq_one(v.z);
    res.w = fpq_one(v.w);
    __builtin_nontemporal_store(res, &out4[idx]);
}

__global__ __launch_bounds__(256) void fpq_tail(const float* __restrict__ in,
                                                float* __restrict__ out,
                                                int start, int n) {
    int idx = start + blockIdx.x * blockDim.x + threadIdx.x;
    if (idx >= n) return;
    out[idx] = fpq_one(in[idx]);
}

extern "C" void kernel_launch(void* const* d_in, const int* in_sizes, int n_in,
                              void* d_out, int out_size, void* d_ws, size_t ws_size,
                              hipStream_t stream) {
    const float* x = (const float*)d_in[0];
    float* out = (float*)d_out;
    int n = in_sizes[0];           // 8192*8192 = 67108864
    int n4 = n / 4;
    if (n4 > 0) {
        int block = 256;
        int grid = (n4 + block - 1) / block;   // 65536 blocks
        fpq_vec4<<<grid, block, 0, stream>>>(x, out, n4);
    }
    int tail_start = n4 * 4;
    int tail = n - tail_start;
    if (tail > 0) {
        fpq_tail<<<1, 64, 0, stream>>>(x, out, tail_start, n);
    }
}